// Round 1
// baseline (360.016 us; speedup 1.0000x reference)
//
#include <hip/hip_runtime.h>

#define NN 2048
#define DD 64
#define BB 64
#define PP 16384
#define TT 262144
#define EPSF 1e-6f

// ---------------- ws layout (bytes) ----------------
// 0       : double acc
// 16      : float bounds[BB+1]      (65)
// 288     : float widths[BB]        (64)
// 544     : float rwidths[BB]       (64)
// 1024    : int   counts[PP]
// 66560   : int   starts[PP]
// 132096  : int   cursor[PP]
// 197632  : int   ev_bin[TT]
// 1246208 : float ev_rem[TT]
// total ~2.3 MB

__device__ __forceinline__ float wave_sum(float x) {
#pragma unroll
    for (int m = 32; m >= 1; m >>= 1) x += __shfl_xor(x, m, 64);
    return x;
}

__global__ void k_bounds(const float* __restrict__ brw, float* __restrict__ bounds,
                         float* __restrict__ widths, float* __restrict__ rwidths) {
    int lane = threadIdx.x;  // 64 threads
    float w = brw[lane];
    float m = w;
#pragma unroll
    for (int s = 32; s >= 1; s >>= 1) m = fmaxf(m, __shfl_xor(m, s, 64));
    float e = expf(w - m);
    float tot = wave_sum(e);
    float sm = e / tot;                       // softmax value
    float c = sm;                             // inclusive prefix sum
#pragma unroll
    for (int off = 1; off < 64; off <<= 1) {
        float t = __shfl_up(c, off, 64);
        if (lane >= off) c += t;
    }
    float cexcl = __shfl_up(c, 1, 64);
    if (lane == 0) cexcl = 0.f;
    if (lane == 0) bounds[0] = 0.f;
    bounds[lane + 1] = c;                     // * LAST_TIME (=1.0)
    float wd = c - cexcl;                     // widths = bounds[1:]-bounds[:-1]
    widths[lane] = wd;
    rwidths[lane] = 1.0f / wd;
}

__global__ void k_hist(const int* __restrict__ epid, int* __restrict__ counts) {
    int t = blockIdx.x * blockDim.x + threadIdx.x;
    if (t < TT) atomicAdd(&counts[epid[t]], 1);
}

__global__ void k_scan(const int* __restrict__ counts, int* __restrict__ starts,
                       int* __restrict__ cursor) {
    __shared__ int waveTot[16];
    __shared__ int waveOff[16];
    int tid = threadIdx.x;          // 1024 threads, 16 entries each
    int base = tid * 16;
    int local[16];
    int s = 0;
#pragma unroll
    for (int k = 0; k < 16; k++) { local[k] = counts[base + k]; s += local[k]; }
    int lane = tid & 63, wid = tid >> 6;
    int incl = s;
#pragma unroll
    for (int off = 1; off < 64; off <<= 1) {
        int t2 = __shfl_up(incl, off, 64);
        if (lane >= off) incl += t2;
    }
    if (lane == 63) waveTot[wid] = incl;
    __syncthreads();
    if (tid == 0) {
        int r = 0;
        for (int w = 0; w < 16; w++) { waveOff[w] = r; r += waveTot[w]; }
    }
    __syncthreads();
    int run = waveOff[wid] + (incl - s);      // exclusive prefix for this thread
#pragma unroll
    for (int k = 0; k < 16; k++) {
        starts[base + k] = run;
        cursor[base + k] = run;
        run += local[k];
    }
}

__global__ void k_scatter(const float* __restrict__ times, const int* __restrict__ epid,
                          const float* __restrict__ bounds, int* __restrict__ cursor,
                          int* __restrict__ ev_bin, float* __restrict__ ev_rem) {
    __shared__ float sb[BB + 1];
    if (threadIdx.x <= BB) sb[threadIdx.x] = bounds[threadIdx.x];
    __syncthreads();
    int t = blockIdx.x * blockDim.x + threadIdx.x;
    if (t >= TT) return;
    float tm = times[t];
    int pid = epid[t];
    int bin = 0;                               // searchsorted(inner, tm, 'right')
#pragma unroll
    for (int k = 1; k < BB; k++) bin += (sb[k] <= tm) ? 1 : 0;
    float rem = tm - sb[bin];
    int pos = atomicAdd(&cursor[pid], 1);
    ev_bin[pos] = bin;
    ev_rem[pos] = rem;
}

__global__ __launch_bounds__(64) void k_pairs(
    const float* __restrict__ x0, const float* __restrict__ v,
    const float* __restrict__ beta, const int* __restrict__ pairs,
    const float* __restrict__ widths, const float* __restrict__ rwidths,
    const int* __restrict__ counts, const int* __restrict__ starts,
    const int* __restrict__ ev_bin, const float* __restrict__ ev_rem,
    double* __restrict__ acc_out) {
    __shared__ float xtb[(BB + 1) * DD];       // 16640 B: xt at all 65 boundaries
    int p = blockIdx.x;
    int lane = threadIdx.x;
    int i = pairs[p];
    int j = pairs[PP + p];
    float bsum = beta[i] + beta[j];
    float xt = x0[i * DD + lane] - x0[j * DD + lane];
    xtb[lane] = xt;
    float n2 = wave_sum(xt * xt);
    float r = sqrtf(n2);
    float numer_prev = r * expf(bsum - r);
    float acc = 0.f;

    const float* vi = v + (size_t)i * DD + lane;
    const float* vj = v + (size_t)j * DD + lane;
    float va = vi[0];
    float vb = vj[0];
    for (int b = 0; b < BB; b++) {
        float va_n = 0.f, vb_n = 0.f;
        if (b + 1 < BB) {                      // 1-ahead prefetch of next v rows
            va_n = vi[(size_t)(b + 1) * NN * DD];
            vb_n = vj[(size_t)(b + 1) * NN * DD];
        }
        float dv = va - vb;
        float dot0 = wave_sum(xt * dv);        // xt_b · dv_b
        xt = fmaf(dv, widths[b], xt);          // xt_{b+1}
        xtb[(b + 1) * DD + lane] = xt;
        float pn = xt * xt, pd = xt * dv;      // ||xt_{b+1}||^2 and xt_{b+1}·dv_b
#pragma unroll
        for (int m = 32; m >= 1; m >>= 1) {
            pn += __shfl_xor(pn, m, 64);
            pd += __shfl_xor(pd, m, 64);
        }
        float rr = sqrtf(pn);
        float numer = rr * expf(bsum - rr);
        acc += numer / (pd + EPSF) - numer_prev / (dot0 + EPSF);
        numer_prev = numer;
        va = va_n;
        vb = vb_n;
    }
    __syncthreads();                            // LDS visibility for event phase

    int st = starts[p], cnt = counts[p];
    float eacc = 0.f;
    for (int e = 0; e < cnt; e++) {
        int bin = ev_bin[st + e];
        float rem = ev_rem[st + e];
        float xb = xtb[bin * DD + lane];
        float xn = xtb[(bin + 1) * DD + lane];
        float dv = (xn - xb) * rwidths[bin];
        float x = fmaf(dv, rem, xb);
        float s2 = wave_sum(x * x);
        eacc += bsum - sqrtf(s2);
    }
    float total = acc - eacc;                   // integral - non_integral (this pair)
    if (lane == 0) atomicAdd(acc_out, (double)total);
}

__global__ void k_finalize(const double* __restrict__ acc, float* __restrict__ out) {
    out[0] = (float)(*acc);
}

extern "C" void kernel_launch(void* const* d_in, const int* in_sizes, int n_in,
                              void* d_out, int out_size, void* d_ws, size_t ws_size,
                              hipStream_t stream) {
    const float* x0     = (const float*)d_in[0];
    const float* v      = (const float*)d_in[1];
    const float* beta   = (const float*)d_in[2];
    const float* brw    = (const float*)d_in[3];
    const float* etimes = (const float*)d_in[4];
    const int*   pairs  = (const int*)d_in[5];
    const int*   epid   = (const int*)d_in[6];

    char* ws = (char*)d_ws;
    double* acc    = (double*)ws;
    float* bounds  = (float*)(ws + 16);
    float* widths  = (float*)(ws + 288);
    float* rwidths = (float*)(ws + 544);
    int* counts    = (int*)(ws + 1024);
    int* starts    = (int*)(ws + 66560);
    int* cursor    = (int*)(ws + 132096);
    int* ev_bin    = (int*)(ws + 197632);
    float* ev_rem  = (float*)(ws + 1246208);

    hipMemsetAsync(ws, 0, 1024 + 4 * PP, stream);   // acc + counts

    hipLaunchKernelGGL(k_bounds, dim3(1), dim3(64), 0, stream, brw, bounds, widths, rwidths);
    hipLaunchKernelGGL(k_hist, dim3(TT / 256), dim3(256), 0, stream, epid, counts);
    hipLaunchKernelGGL(k_scan, dim3(1), dim3(1024), 0, stream, counts, starts, cursor);
    hipLaunchKernelGGL(k_scatter, dim3(TT / 256), dim3(256), 0, stream, etimes, epid, bounds,
                       cursor, ev_bin, ev_rem);
    hipLaunchKernelGGL(k_pairs, dim3(PP), dim3(64), 0, stream, x0, v, beta, pairs,
                       widths, rwidths, counts, starts, ev_bin, ev_rem, acc);
    hipLaunchKernelGGL(k_finalize, dim3(1), dim3(1), 0, stream, acc, (float*)d_out);
}

// Round 2
// 142.694 us; speedup vs baseline: 2.5230x; 2.5230x over previous
//
#include <hip/hip_runtime.h>

#define NN 2048
#define DD 64
#define BB 64
#define PP 16384
#define TT 262144
#define EPSF 1e-6f

// ---------------- ws layout (bytes) ----------------
// 0       : double acc
// 64      : float bounds[BB+1]   (65)
// 384     : float widths[BB]     (64)
// 640     : float innerPad[64]   (inner[0..62], [63]=+INF)
// 1024    : int   counts[PP]
// 66560   : int   starts[PP]
// 132096  : int   cursor[PP]
// 197632  : int   ev_bin[TT]
// 1246208 : float ev_rem[TT]
// total ~2.3 MB

template <int CTRL>
__device__ __forceinline__ float dpp_add(float x) {
    int y = __builtin_amdgcn_update_dpp(0, __float_as_int(x), CTRL, 0xF, 0xF, true);
    return x + __int_as_float(y);
}

// full 64-lane sum, result on all lanes; 4 VALU DPP + 1 ds_swizzle + 1 bpermute
__device__ __forceinline__ float reduce1(float a) {
    a = dpp_add<0xB1>(a);    // quad_perm xor1
    a = dpp_add<0x4E>(a);    // quad_perm xor2
    a = dpp_add<0x141>(a);   // row_half_mirror (sum of 8)
    a = dpp_add<0x140>(a);   // row_mirror (sum of 16)
    a += __int_as_float(__builtin_amdgcn_ds_swizzle(__float_as_int(a), 0x401F));  // xor16
    a += __shfl_xor(a, 32, 64);
    return a;
}

__device__ __forceinline__ void reduce2(float& a, float& b) {
    a = dpp_add<0xB1>(a);  b = dpp_add<0xB1>(b);
    a = dpp_add<0x4E>(a);  b = dpp_add<0x4E>(b);
    a = dpp_add<0x141>(a); b = dpp_add<0x141>(b);
    a = dpp_add<0x140>(a); b = dpp_add<0x140>(b);
    a += __int_as_float(__builtin_amdgcn_ds_swizzle(__float_as_int(a), 0x401F));
    b += __int_as_float(__builtin_amdgcn_ds_swizzle(__float_as_int(b), 0x401F));
    a += __shfl_xor(a, 32, 64);
    b += __shfl_xor(b, 32, 64);
}

__device__ __forceinline__ float rlane(float v, int l) {
    return __int_as_float(__builtin_amdgcn_readlane(__float_as_int(v), l));
}

__global__ void k_bounds(const float* __restrict__ brw, float* __restrict__ bounds,
                         float* __restrict__ widths, float* __restrict__ innerPad) {
    int lane = threadIdx.x;  // 64 threads
    float w = brw[lane];
    float m = w;
#pragma unroll
    for (int s = 32; s >= 1; s >>= 1) m = fmaxf(m, __shfl_xor(m, s, 64));
    float e = expf(w - m);
    float tot = e;
#pragma unroll
    for (int s = 32; s >= 1; s >>= 1) tot += __shfl_xor(tot, s, 64);
    float sm = e / tot;
    float c = sm;  // inclusive prefix sum
#pragma unroll
    for (int off = 1; off < 64; off <<= 1) {
        float t = __shfl_up(c, off, 64);
        if (lane >= off) c += t;
    }
    float cexcl = __shfl_up(c, 1, 64);
    if (lane == 0) cexcl = 0.f;
    if (lane == 0) bounds[0] = 0.f;
    bounds[lane + 1] = c;
    widths[lane] = c - cexcl;
    innerPad[lane] = (lane == 63) ? 3.4e38f : c;  // inner = bounds[1..63]
}

__global__ void k_hist(const int* __restrict__ epid, int* __restrict__ counts) {
    int t = blockIdx.x * blockDim.x + threadIdx.x;
    if (t < TT) atomicAdd(&counts[epid[t]], 1);
}

__global__ void k_scan(const int* __restrict__ counts, int* __restrict__ starts,
                       int* __restrict__ cursor) {
    __shared__ int waveTot[16];
    __shared__ int waveOff[16];
    int tid = threadIdx.x;  // 1024 threads, 16 entries each
    int base = tid * 16;
    int local[16];
    int s = 0;
#pragma unroll
    for (int k = 0; k < 16; k++) { local[k] = counts[base + k]; s += local[k]; }
    int lane = tid & 63, wid = tid >> 6;
    int incl = s;
#pragma unroll
    for (int off = 1; off < 64; off <<= 1) {
        int t2 = __shfl_up(incl, off, 64);
        if (lane >= off) incl += t2;
    }
    if (lane == 63) waveTot[wid] = incl;
    __syncthreads();
    if (tid == 0) {
        int r = 0;
        for (int w = 0; w < 16; w++) { waveOff[w] = r; r += waveTot[w]; }
    }
    __syncthreads();
    int run = waveOff[wid] + (incl - s);
#pragma unroll
    for (int k = 0; k < 16; k++) {
        starts[base + k] = run;
        cursor[base + k] = run;
        run += local[k];
    }
}

__global__ void k_scatter(const float* __restrict__ times, const int* __restrict__ epid,
                          const float* __restrict__ bounds, const float* __restrict__ innerPad,
                          int* __restrict__ cursor,
                          int* __restrict__ ev_bin, float* __restrict__ ev_rem) {
    __shared__ float si[64];
    __shared__ float sb[BB + 1];
    if (threadIdx.x < 64) si[threadIdx.x] = innerPad[threadIdx.x];
    if (threadIdx.x <= BB) sb[threadIdx.x] = bounds[threadIdx.x];
    __syncthreads();
    int t = blockIdx.x * blockDim.x + threadIdx.x;
    float tm = times[t];
    int c = 0;  // searchsorted(inner, tm, 'right'), binary over padded 64
#pragma unroll
    for (int s = 32; s >= 1; s >>= 1)
        if (si[c + s - 1] <= tm) c += s;
    float rem = tm - sb[c];
    int pos = atomicAdd(&cursor[epid[t]], 1);
    ev_bin[pos] = c;
    ev_rem[pos] = rem;
}

__global__ __launch_bounds__(256) void k_pairs(
    const float* __restrict__ x0, const float* __restrict__ v,
    const float* __restrict__ beta, const int* __restrict__ pairs,
    const float* __restrict__ widths,
    const int* __restrict__ counts, const int* __restrict__ starts,
    const int* __restrict__ ev_bin, const float* __restrict__ ev_rem,
    double* __restrict__ acc_out) {
    __shared__ double bacc[4];
    int wid = threadIdx.x >> 6;
    int lane = threadIdx.x & 63;
    int p = blockIdx.x * 4 + wid;

    int i = pairs[p];
    int j = pairs[PP + p];
    float bsum = beta[i] + beta[j];
    float xt = x0[i * DD + lane] - x0[j * DD + lane];
    float w_all = widths[lane];

    float n2 = reduce1(xt * xt);
    float rr = __builtin_amdgcn_sqrtf(n2);
    float numer_prev = rr * __expf(bsum - rr);

    const size_t S = (size_t)NN * DD;
    const float* vi = v + (size_t)i * DD + lane;
    const float* vj = v + (size_t)j * DD + lane;
    float a0 = vi[0], c0 = vj[0];
    float a1 = vi[S], c1 = vj[S];

    float s_n2 = 0.f, s_d0 = 0.f, s_q = 0.f;  // lane b holds bin b's scalars
    float acc = 0.f;

    for (int b = 0; b < BB; b += 2) {
        int pf0 = min(b + 2, BB - 1), pf1 = min(b + 3, BB - 1);
        float na0 = vi[(size_t)pf0 * S], nc0 = vj[(size_t)pf0 * S];
        float na1 = vi[(size_t)pf1 * S], nc1 = vj[(size_t)pf1 * S];

        // ---- bin b
        {
            float dv = a0 - c0;
            float d0 = xt * dv, qq = dv * dv;
            reduce2(d0, qq);
            float wb = rlane(w_all, b);
            if (lane == b) { s_n2 = n2; s_d0 = d0; s_q = qq; }
            xt = fmaf(dv, wb, xt);
            float pd = fmaf(wb, qq, d0);
            float n2n = fmaxf(fmaf(wb, fmaf(wb, qq, 2.f * d0), n2), 0.f);
            float r1 = __builtin_amdgcn_sqrtf(n2n);
            float numer = r1 * __expf(bsum - r1);
            acc += numer * __builtin_amdgcn_rcpf(pd + EPSF)
                 - numer_prev * __builtin_amdgcn_rcpf(d0 + EPSF);
            numer_prev = numer;
            n2 = n2n;
        }
        // ---- bin b+1
        {
            float dv = a1 - c1;
            float d0 = xt * dv, qq = dv * dv;
            reduce2(d0, qq);
            float wb = rlane(w_all, b + 1);
            if (lane == b + 1) { s_n2 = n2; s_d0 = d0; s_q = qq; }
            xt = fmaf(dv, wb, xt);
            float pd = fmaf(wb, qq, d0);
            float n2n = fmaxf(fmaf(wb, fmaf(wb, qq, 2.f * d0), n2), 0.f);
            float r1 = __builtin_amdgcn_sqrtf(n2n);
            float numer = r1 * __expf(bsum - r1);
            acc += numer * __builtin_amdgcn_rcpf(pd + EPSF)
                 - numer_prev * __builtin_amdgcn_rcpf(d0 + EPSF);
            numer_prev = numer;
            n2 = n2n;
        }
        a0 = na0; c0 = nc0; a1 = na1; c1 = nc1;
    }

    // ---- events: 64 per wave in parallel, one lane per event
    int st = starts[p], cnt = counts[p];
    float eacc = 0.f;
    for (int base = 0; base < cnt; base += 64) {
        int e = base + lane;
        bool valid = e < cnt;
        int idx = st + min(e, cnt - 1);
        int bin = ev_bin[idx];
        float rem = ev_rem[idx];
        float gn2 = __shfl(s_n2, bin, 64);
        float gd0 = __shfl(s_d0, bin, 64);
        float gq  = __shfl(s_q, bin, 64);
        float d2 = fmaxf(fmaf(rem, fmaf(rem, gq, 2.f * gd0), gn2), 0.f);
        float ds = __builtin_amdgcn_sqrtf(d2);
        eacc += valid ? (bsum - ds) : 0.f;
    }
    eacc = reduce1(eacc);

    if (lane == 0) bacc[wid] = (double)(acc - eacc);
    __syncthreads();
    if (threadIdx.x == 0)
        atomicAdd(acc_out, bacc[0] + bacc[1] + bacc[2] + bacc[3]);
}

__global__ void k_finalize(const double* __restrict__ acc, float* __restrict__ out) {
    out[0] = (float)(*acc);
}

extern "C" void kernel_launch(void* const* d_in, const int* in_sizes, int n_in,
                              void* d_out, int out_size, void* d_ws, size_t ws_size,
                              hipStream_t stream) {
    const float* x0     = (const float*)d_in[0];
    const float* v      = (const float*)d_in[1];
    const float* beta   = (const float*)d_in[2];
    const float* brw    = (const float*)d_in[3];
    const float* etimes = (const float*)d_in[4];
    const int*   pairs  = (const int*)d_in[5];
    const int*   epid   = (const int*)d_in[6];

    char* ws = (char*)d_ws;
    double* acc     = (double*)ws;
    float* bounds   = (float*)(ws + 64);
    float* widths   = (float*)(ws + 384);
    float* innerPad = (float*)(ws + 640);
    int* counts     = (int*)(ws + 1024);
    int* starts     = (int*)(ws + 66560);
    int* cursor     = (int*)(ws + 132096);
    int* ev_bin     = (int*)(ws + 197632);
    float* ev_rem   = (float*)(ws + 1246208);

    hipMemsetAsync(ws, 0, 1024 + 4 * PP, stream);  // acc + counts

    hipLaunchKernelGGL(k_bounds, dim3(1), dim3(64), 0, stream, brw, bounds, widths, innerPad);
    hipLaunchKernelGGL(k_hist, dim3(TT / 256), dim3(256), 0, stream, epid, counts);
    hipLaunchKernelGGL(k_scan, dim3(1), dim3(1024), 0, stream, counts, starts, cursor);
    hipLaunchKernelGGL(k_scatter, dim3(TT / 256), dim3(256), 0, stream, etimes, epid, bounds,
                       innerPad, cursor, ev_bin, ev_rem);
    hipLaunchKernelGGL(k_pairs, dim3(PP / 4), dim3(256), 0, stream, x0, v, beta, pairs,
                       widths, counts, starts, ev_bin, ev_rem, acc);
    hipLaunchKernelGGL(k_finalize, dim3(1), dim3(1), 0, stream, acc, (float*)d_out);
}

// Round 3
// 108.708 us; speedup vs baseline: 3.3118x; 1.3126x over previous
//
#include <hip/hip_runtime.h>

#define NN 2048
#define DD 64
#define BB 64
#define PP 16384
#define TT 262144
#define EPSF 1e-6f
#define SS ((size_t)NN * DD)  // floats between consecutive bins of v

// ---------------- ws layout (bytes) ----------------
// 0    : double acc
// 64   : float bounds[65]
// 384  : float widths[64]
// 640  : float innerPad[64]   (inner[0..62], [63]=+INF)
// 1024 : float4 table[PP*BB]  (n2_left, d0, qq, bsum)  = 16.8 MB

template <int CTRL, int RM = 0xF, bool BC = true>
__device__ __forceinline__ float dpp_add(float x) {
    int y = __builtin_amdgcn_update_dpp(0, __float_as_int(x), CTRL, RM, 0xF, BC);
    return x + __int_as_float(y);
}

// full 64-lane sum, result on all lanes
__device__ __forceinline__ float reduce1(float a) {
    a = dpp_add<0xB1>(a);    // quad_perm xor1
    a = dpp_add<0x4E>(a);    // quad_perm xor2
    a = dpp_add<0x141>(a);   // row_half_mirror (sum of 8)
    a = dpp_add<0x140>(a);   // row_mirror (sum of 16)
    a += __int_as_float(__builtin_amdgcn_ds_swizzle(__float_as_int(a), 0x401F));  // xor16
    a += __shfl_xor(a, 32, 64);
    return a;
}

// 64-lane inclusive prefix sum (canonical 6-DPP scan)
__device__ __forceinline__ float incl_scan(float x) {
    x = dpp_add<0x111>(x);             // row_shr:1
    x = dpp_add<0x112>(x);             // row_shr:2
    x = dpp_add<0x114>(x);             // row_shr:4
    x = dpp_add<0x118>(x);             // row_shr:8
    x = dpp_add<0x142, 0xA, false>(x); // row_bcast:15 -> rows 1,3
    x = dpp_add<0x143, 0xC, false>(x); // row_bcast:31 -> rows 2,3
    return x;
}

__global__ void k_bounds(const float* __restrict__ brw, float* __restrict__ bounds,
                         float* __restrict__ widths, float* __restrict__ innerPad) {
    int lane = threadIdx.x;  // 64 threads
    float w = brw[lane];
    float m = w;
#pragma unroll
    for (int s = 32; s >= 1; s >>= 1) m = fmaxf(m, __shfl_xor(m, s, 64));
    float e = expf(w - m);
    float tot = e;
#pragma unroll
    for (int s = 32; s >= 1; s >>= 1) tot += __shfl_xor(tot, s, 64);
    float sm = e / tot;
    float c = sm;  // inclusive prefix sum
#pragma unroll
    for (int off = 1; off < 64; off <<= 1) {
        float t = __shfl_up(c, off, 64);
        if (lane >= off) c += t;
    }
    float cexcl = __shfl_up(c, 1, 64);
    if (lane == 0) cexcl = 0.f;
    if (lane == 0) bounds[0] = 0.f;
    bounds[lane + 1] = c;
    widths[lane] = c - cexcl;
    innerPad[lane] = (lane == 63) ? 3.4e38f : c;  // inner = bounds[1..63]
}

__global__ __launch_bounds__(256) void k_pairs(
    const float* __restrict__ x0, const float* __restrict__ v,
    const float* __restrict__ beta, const int* __restrict__ pairs,
    const float* __restrict__ widths, float4* __restrict__ table,
    double* __restrict__ acc_out) {
    __shared__ float tiles[4][2][8][66];  // [wave][d0|qq][bin-in-chunk][writer lane] (+2 pad)
    __shared__ double bacc[4];
    const int wid = threadIdx.x >> 6;
    const int lane = threadIdx.x & 63;
    const int p = blockIdx.x * 4 + wid;

    const int i = pairs[p];
    const int j = pairs[PP + p];
    const float bsum = beta[i] + beta[j];

    float dx0 = x0[i * DD + lane] - x0[j * DD + lane];
    float xt = dx0;
    float n2_0 = reduce1(dx0 * dx0);
    float rr0 = __builtin_amdgcn_sqrtf(n2_0);
    float numer0 = rr0 * __expf(bsum - rr0);

    const float* __restrict__ pi = v + (size_t)i * DD + lane;
    const float* __restrict__ pj = v + (size_t)j * DD + lane;

    float (*t_d0)[66] = tiles[wid][0];
    float (*t_qq)[66] = tiles[wid][1];

    const int br = lane >> 3;            // reader: bin within chunk
    const int e8 = (lane & 7) * 8;       // reader: column start
    const int src_pl = (lane & 7) << 5;  // bpermute byte addr: pull from lane 8*(l&7)

    float d0r = 0.f, qqr = 0.f;  // lane b ends holding bin b's reduced d0, qq

    float curA[8], curB[8];
#pragma unroll
    for (int b = 0; b < 8; b++) {
        curA[b] = pi[(size_t)b * SS];
        curB[b] = pj[(size_t)b * SS];
    }

#pragma unroll
    for (int c = 0; c < 8; c++) {
        // phase 1: per-lane partials for 8 bins -> LDS tile (conflict-free writes)
#pragma unroll
        for (int b = 0; b < 8; b++) {
            float dv = curA[b] - curB[b];
            float w = widths[c * 8 + b];
            t_d0[b][lane] = xt * dv;
            t_qq[b][lane] = dv * dv;
            xt = fmaf(dv, w, xt);
        }
        // issue next chunk's 16 loads (hidden under phase 2 + TLP)
        if (c < 7) {
#pragma unroll
            for (int b = 0; b < 8; b++) {
                curA[b] = pi[(size_t)((c + 1) * 8 + b) * SS];
                curB[b] = pj[(size_t)((c + 1) * 8 + b) * SS];
            }
        }
        // phase 2: transpose-reduce; 8 lanes per bin, each sums 8 columns
        const float* r0 = &t_d0[br][e8];
        const float* r1 = &t_qq[br][e8];
        float s0 = 0.f, s1 = 0.f;
#pragma unroll
        for (int k = 0; k < 8; k += 2) {
            float2 a = *(const float2*)(r0 + k);
            float2 b2 = *(const float2*)(r1 + k);
            s0 += a.x + a.y;
            s1 += b2.x + b2.y;
        }
        // sum across the 8 lanes of the group: xor1, xor2, xor7 (row_half_mirror)
        s0 = dpp_add<0xB1>(s0);  s1 = dpp_add<0xB1>(s1);
        s0 = dpp_add<0x4E>(s0);  s1 = dpp_add<0x4E>(s1);
        s0 = dpp_add<0x141>(s0); s1 = dpp_add<0x141>(s1);
        // place bin (8c+k) result into lane 8c+k
        float g0 = __int_as_float(__builtin_amdgcn_ds_bpermute(src_pl, __float_as_int(s0)));
        float g1 = __int_as_float(__builtin_amdgcn_ds_bpermute(src_pl, __float_as_int(s1)));
        if ((lane >> 3) == c) { d0r = g0; qqr = g1; }
    }

    // phase 3: all 64 bins' scalar math lane-parallel
    float wl = widths[lane];
    float tt = wl * fmaf(wl, qqr, 2.f * d0r);     // n2 increment of bin `lane`
    float incl = incl_scan(tt);
    float n2L = fmaxf(n2_0 + (incl - tt), 0.f);   // left-boundary norm^2
    float n2R = fmaxf(n2_0 + incl, 0.f);          // right-boundary norm^2
    float rrR = __builtin_amdgcn_sqrtf(n2R);
    float numerR = rrR * __expf(bsum - rrR);
    int shaddr = ((lane + 63) & 63) << 2;         // pull from lane-1
    float numerL = __int_as_float(__builtin_amdgcn_ds_bpermute(shaddr, __float_as_int(numerR)));
    numerL = (lane == 0) ? numer0 : numerL;
    float pd = fmaf(wl, qqr, d0r);                // dot1 = d0 + w*qq
    float term = numerR * __builtin_amdgcn_rcpf(pd + EPSF)
               - numerL * __builtin_amdgcn_rcpf(d0r + EPSF);
    float acc = reduce1(term);

    table[(size_t)p * BB + lane] = make_float4(n2L, d0r, qqr, bsum);

    if (lane == 0) bacc[wid] = (double)acc;
    __syncthreads();
    if (threadIdx.x == 0)
        atomicAdd(acc_out, bacc[0] + bacc[1] + bacc[2] + bacc[3]);
}

__global__ __launch_bounds__(256) void k_events(
    const float* __restrict__ times, const int* __restrict__ epid,
    const float* __restrict__ bounds, const float* __restrict__ innerPad,
    const float4* __restrict__ table, double* __restrict__ acc_out) {
    __shared__ float si[64];
    __shared__ float sb[BB + 1];
    __shared__ double wacc[4];
    int tid = threadIdx.x;
    if (tid < 64) si[tid] = innerPad[tid];
    if (tid <= BB) sb[tid] = bounds[tid];
    __syncthreads();
    int t = blockIdx.x * 256 + tid;
    float tm = times[t];
    int pid = epid[t];
    int c = 0;  // searchsorted(inner, tm, 'right') via binary search over padded 64
#pragma unroll
    for (int s = 32; s >= 1; s >>= 1)
        if (si[c + s - 1] <= tm) c += s;
    float rem = tm - sb[c];
    float4 en = table[(size_t)pid * BB + c];
    float d2 = fmaxf(fmaf(rem, fmaf(rem, en.z, 2.f * en.y), en.x), 0.f);
    float val = en.w - __builtin_amdgcn_sqrtf(d2);  // bsum - dist
    val = reduce1(val);
    if ((tid & 63) == 0) wacc[tid >> 6] = (double)val;
    __syncthreads();
    if (tid == 0)
        atomicAdd(acc_out, -(wacc[0] + wacc[1] + wacc[2] + wacc[3]));
}

__global__ void k_finalize(const double* __restrict__ acc, float* __restrict__ out) {
    out[0] = (float)(*acc);
}

extern "C" void kernel_launch(void* const* d_in, const int* in_sizes, int n_in,
                              void* d_out, int out_size, void* d_ws, size_t ws_size,
                              hipStream_t stream) {
    const float* x0     = (const float*)d_in[0];
    const float* v      = (const float*)d_in[1];
    const float* beta   = (const float*)d_in[2];
    const float* brw    = (const float*)d_in[3];
    const float* etimes = (const float*)d_in[4];
    const int*   pairs  = (const int*)d_in[5];
    const int*   epid   = (const int*)d_in[6];

    char* ws = (char*)d_ws;
    double* acc     = (double*)ws;
    float* bounds   = (float*)(ws + 64);
    float* widths   = (float*)(ws + 384);
    float* innerPad = (float*)(ws + 640);
    float4* table   = (float4*)(ws + 1024);

    hipMemsetAsync(ws, 0, 64, stream);  // acc

    hipLaunchKernelGGL(k_bounds, dim3(1), dim3(64), 0, stream, brw, bounds, widths, innerPad);
    hipLaunchKernelGGL(k_pairs, dim3(PP / 4), dim3(256), 0, stream, x0, v, beta, pairs,
                       widths, table, acc);
    hipLaunchKernelGGL(k_events, dim3(TT / 256), dim3(256), 0, stream, etimes, epid,
                       bounds, innerPad, table, acc);
    hipLaunchKernelGGL(k_finalize, dim3(1), dim3(1), 0, stream, acc, (float*)d_out);
}